// Round 3
// baseline (1676.027 us; speedup 1.0000x reference)
//
#include <hip/hip_runtime.h>

#define NN 50000
#define EE 600000

__device__ inline void fma4(float4& a, float s, const float4 w) {
  a.x = fmaf(s, w.x, a.x);
  a.y = fmaf(s, w.y, a.y);
  a.z = fmaf(s, w.z, a.z);
  a.w = fmaf(s, w.w, a.w);
}
__device__ inline void add4(float4& a, const float4 b) {
  a.x += b.x; a.y += b.y; a.z += b.z; a.w += b.w;
}

// ---------- graph preprocessing ----------
// counts out-degree (src) and in-degree (dst) in one pass
__global__ void count2_k(const int* __restrict__ ei, int* __restrict__ cnt_s,
                         int* __restrict__ cnt_d) {
  int e = blockIdx.x * 256 + threadIdx.x;
  if (e < EE) {
    atomicAdd(&cnt_s[ei[e]], 1);
    atomicAdd(&cnt_d[ei[EE + e]], 1);
  }
}

__global__ void scan_k(const int* __restrict__ cnt, int* __restrict__ rs) {
  __shared__ int ls[1024];
  const int t = threadIdx.x;
  const int STRIP = (NN + 1023) >> 10;  // 49
  int i0 = t * STRIP;
  int i1 = min(i0 + STRIP, NN);
  int s = 0;
  for (int i = i0; i < i1; ++i) s += cnt[i];
  ls[t] = s;
  __syncthreads();
  for (int off = 1; off < 1024; off <<= 1) {
    int v = (t >= off) ? ls[t - off] : 0;
    __syncthreads();
    ls[t] += v;
    __syncthreads();
  }
  int run = (t == 0) ? 0 : ls[t - 1];
  for (int i = i0; i < i1; ++i) { rs[i] = run; run += cnt[i]; }
  if (t == 0) rs[NN] = EE;
}

// CSC order (grouped by src) with each edge's CSR (dst-grouped) slot.
__global__ void fill2_k(const int* __restrict__ ei, const float* __restrict__ ew,
                        int* __restrict__ cur_s, int* __restrict__ cur_d,
                        int* __restrict__ srcs, int2* __restrict__ pw) {
  int e = blockIdx.x * 256 + threadIdx.x;
  if (e < EE) {
    int s = ei[e], d = ei[EE + e];
    int pc = atomicAdd(&cur_s[s], 1);
    int pr = atomicAdd(&cur_d[d], 1);
    srcs[pc] = s;
    int2 v;
    v.x = pr;
    v.y = __float_as_int(ew[e]);
    pw[pc] = v;
  }
}

// CSR fill (fallback fused path only)
__global__ void fill_k(const int* __restrict__ ei, const float* __restrict__ ew,
                       int* __restrict__ cur, int2* __restrict__ esw) {
  int e = blockIdx.x * 256 + threadIdx.x;
  if (e < EE) {
    int d = ei[EE + e];
    int p = atomicAdd(&cur[d], 1);
    int2 v;
    v.x = ei[e];
    v.y = __float_as_int(ew[e]);
    esw[p] = v;
  }
}

// ---------- fused dual GEMM: Tl = bnrelu(H)@Wl, Tr = bnrelu(H)@Wr ----------
template <int F>
__global__ __launch_bounds__(256, 3) void gemm_dual(
    const float* __restrict__ H, const float* __restrict__ Wl,
    const float* __restrict__ Wr, const float* __restrict__ ss,
    float* __restrict__ Tl, float* __restrict__ Tr) {
  constexpr int K = 128;
  constexpr int Kc = 32;
  constexpr int TX = F / 4;
  constexpr int TY = 256 / TX;
  constexpr int ROWS = TY * 8;
  constexpr int HS = ROWS + 4;
  __shared__ __align__(16) float Wls[Kc][F];
  __shared__ __align__(16) float Wrs[Kc][F];
  __shared__ __align__(16) float Hs[Kc][HS];
  const int tid = threadIdx.x;
  const int tx = tid % TX, ty = tid / TX;
  const int n0 = blockIdx.x * ROWS;

  const float4 z4 = {0.f, 0.f, 0.f, 0.f};
  float4 aAA[4], aAB[4], aBA[4], aBB[4];
#pragma unroll
  for (int r = 0; r < 4; ++r) { aAA[r] = z4; aAB[r] = z4; aBA[r] = z4; aBB[r] = z4; }

  for (int kc = 0; kc < K; kc += Kc) {
    __syncthreads();
    for (int idx = tid; idx < Kc * (F / 4); idx += 256) {
      int k = idx / (F / 4), c = idx % (F / 4);
      ((float4*)(&Wls[k][0]))[c] = ((const float4*)Wl)[(kc + k) * (F / 4) + c];
      ((float4*)(&Wrs[k][0]))[c] = ((const float4*)Wr)[(kc + k) * (F / 4) + c];
    }
    for (int idx = tid; idx < ROWS * 8; idx += 256) {
      int i = idx >> 3, k4 = idx & 7;
      int nrow = n0 + i;
      float4 hv = z4;
      if (nrow < NN) hv = ((const float4*)H)[nrow * 32 + (kc >> 2) + k4];
      if (ss) {
        int gk = kc + k4 * 4;
        hv.x = fmaxf(fmaf(hv.x, ss[gk + 0], ss[128 + gk + 0]), 0.f);
        hv.y = fmaxf(fmaf(hv.y, ss[gk + 1], ss[128 + gk + 1]), 0.f);
        hv.z = fmaxf(fmaf(hv.z, ss[gk + 2], ss[128 + gk + 2]), 0.f);
        hv.w = fmaxf(fmaf(hv.w, ss[gk + 3], ss[128 + gk + 3]), 0.f);
      }
      Hs[k4 * 4 + 0][i] = hv.x;
      Hs[k4 * 4 + 1][i] = hv.y;
      Hs[k4 * 4 + 2][i] = hv.z;
      Hs[k4 * 4 + 3][i] = hv.w;
    }
    __syncthreads();
#pragma unroll 4
    for (int k = 0; k < Kc; ++k) {
      float4 wA = *(const float4*)&Wls[k][tx * 4];
      float4 wB = *(const float4*)&Wrs[k][tx * 4];
      float4 hA = *(const float4*)&Hs[k][ty * 4];
      float4 hB = *(const float4*)&Hs[k][ROWS / 2 + ty * 4];
      fma4(aAA[0], hA.x, wA); fma4(aAA[1], hA.y, wA); fma4(aAA[2], hA.z, wA); fma4(aAA[3], hA.w, wA);
      fma4(aAB[0], hA.x, wB); fma4(aAB[1], hA.y, wB); fma4(aAB[2], hA.z, wB); fma4(aAB[3], hA.w, wB);
      fma4(aBA[0], hB.x, wA); fma4(aBA[1], hB.y, wA); fma4(aBA[2], hB.z, wA); fma4(aBA[3], hB.w, wA);
      fma4(aBB[0], hB.x, wB); fma4(aBB[1], hB.y, wB); fma4(aBB[2], hB.z, wB); fma4(aBB[3], hB.w, wB);
    }
  }
  float4* Tl4 = (float4*)Tl;
  float4* Tr4 = (float4*)Tr;
#pragma unroll
  for (int r = 0; r < 4; ++r) {
    int nA = n0 + ty * 4 + r;
    if (nA < NN) { Tl4[nA * TX + tx] = aAA[r]; Tr4[nA * TX + tx] = aAB[r]; }
    int nB = n0 + ROWS / 2 + ty * 4 + r;
    if (nB < NN) { Tl4[nB * TX + tx] = aBA[r]; Tr4[nB * TX + tx] = aBB[r]; }
  }
}

// ---------- pass 1: CSC-ordered edge gather, scatter to CSR msg slot ----------
// Reads of Tl stream (edges sorted by src => heavy L1/L2 reuse); writes are
// scattered full-line stores with no dependent consumer (fire-and-forget).
template <int F4>
__global__ __launch_bounds__(256, 8) void edge_scatter(
    const float* __restrict__ Tl, const int* __restrict__ srcs,
    const int2* __restrict__ pw, float* __restrict__ msg) {
  int gid = blockIdx.x * 256 + threadIdx.x;
  int e = gid / F4;
  int c = gid % F4;
  if (e < EE) {
    int s = srcs[e];
    int2 p = pw[e];
    float w = __int_as_float(p.y);
    float4 t = ((const float4*)Tl)[(size_t)s * F4 + c];
    float4 m;
    m.x = w * t.x; m.y = w * t.y; m.z = w * t.z; m.w = w * t.w;
    ((float4*)msg)[(size_t)p.x * F4 + c] = m;
  }
}

// ---------- pass 2: contiguous segmented reduce + combine (+BN stats) ----------
template <int F4, bool STATS>
__global__ __launch_bounds__(256, 8) void seg_reduce(
    const float* __restrict__ msg, const float* __restrict__ Tr,
    const int* __restrict__ rs, const float* __restrict__ bias,
    float* __restrict__ out, float* __restrict__ stats) {
  constexpr int NODES = 256 / F4;
  const int tid = threadIdx.x;
  const int c = tid % F4;
  const int ni = tid / F4;
  const int n = blockIdx.x * NODES + ni;
  const float4* M4 = (const float4*)msg;
  const float4* Tr4 = (const float4*)Tr;
  const float4* b4 = (const float4*)bias;
  float4 v = {0.f, 0.f, 0.f, 0.f};
  if (n < NN) {
    int r0 = rs[n], r1 = rs[n + 1];
    float4 acc = {0.f, 0.f, 0.f, 0.f};
    int j = r0;
    for (; j + 4 <= r1; j += 4) {
      float4 t0 = M4[(size_t)(j + 0) * F4 + c];
      float4 t1 = M4[(size_t)(j + 1) * F4 + c];
      float4 t2 = M4[(size_t)(j + 2) * F4 + c];
      float4 t3 = M4[(size_t)(j + 3) * F4 + c];
      add4(acc, t0); add4(acc, t1); add4(acc, t2); add4(acc, t3);
    }
    for (; j < r1; ++j) add4(acc, M4[(size_t)j * F4 + c]);
    float inv = 1.0f / fmaxf((float)(r1 - r0), 1.0f);
    float4 t = Tr4[(size_t)n * F4 + c];
    float4 bb = b4[c];
    v.x = fmaf(acc.x, inv, t.x + bb.x);
    v.y = fmaf(acc.y, inv, t.y + bb.y);
    v.z = fmaf(acc.z, inv, t.z + bb.z);
    v.w = fmaf(acc.w, inv, t.w + bb.w);
    ((float4*)out)[(size_t)n * F4 + c] = v;
  }
  if constexpr (STATS) {  // only instantiated with F4=32 (2 nodes per wave)
    __shared__ float4 redS[4][32];
    __shared__ float4 redQ[4][32];
    float4 q;
    q.x = v.x * v.x; q.y = v.y * v.y; q.z = v.z * v.z; q.w = v.w * v.w;
    float4 s = v;
    s.x += __shfl_xor(s.x, 32, 64); s.y += __shfl_xor(s.y, 32, 64);
    s.z += __shfl_xor(s.z, 32, 64); s.w += __shfl_xor(s.w, 32, 64);
    q.x += __shfl_xor(q.x, 32, 64); q.y += __shfl_xor(q.y, 32, 64);
    q.z += __shfl_xor(q.z, 32, 64); q.w += __shfl_xor(q.w, 32, 64);
    const int lane = tid & 63, wid = tid >> 6;
    if (lane < 32) { redS[wid][lane] = s; redQ[wid][lane] = q; }
    __syncthreads();
    if (tid < 32) {
      float4 S = redS[0][tid];
      float4 Q = redQ[0][tid];
#pragma unroll
      for (int w2 = 1; w2 < 4; ++w2) {
        S.x += redS[w2][tid].x; S.y += redS[w2][tid].y;
        S.z += redS[w2][tid].z; S.w += redS[w2][tid].w;
        Q.x += redQ[w2][tid].x; Q.y += redQ[w2][tid].y;
        Q.z += redQ[w2][tid].z; Q.w += redQ[w2][tid].w;
      }
      atomicAdd(&stats[tid * 4 + 0], S.x); atomicAdd(&stats[tid * 4 + 1], S.y);
      atomicAdd(&stats[tid * 4 + 2], S.z); atomicAdd(&stats[tid * 4 + 3], S.w);
      atomicAdd(&stats[128 + tid * 4 + 0], Q.x); atomicAdd(&stats[128 + tid * 4 + 1], Q.y);
      atomicAdd(&stats[128 + tid * 4 + 2], Q.z); atomicAdd(&stats[128 + tid * 4 + 3], Q.w);
    }
  }
}

// ---------- fallback fused gather (used only if ws too small for msg) ----------
template <int F4, bool STATS>
__global__ __launch_bounds__(256, 8) void gather_combine(
    const float* __restrict__ Tl, const float* __restrict__ Tr,
    const int* __restrict__ rs, const int2* __restrict__ esw,
    const float* __restrict__ bias,
    float* __restrict__ out, float* __restrict__ stats) {
  constexpr int NODES = 256 / F4;
  const int tid = threadIdx.x;
  const int c = tid % F4;
  const int ni = tid / F4;
  const int n = blockIdx.x * NODES + ni;
  const float4* Tl4 = (const float4*)Tl;
  const float4* Tr4 = (const float4*)Tr;
  const float4* b4 = (const float4*)bias;
  float4 v = {0.f, 0.f, 0.f, 0.f};
  if (n < NN) {
    int r0 = rs[n], r1 = rs[n + 1];
    float4 acc = {0.f, 0.f, 0.f, 0.f};
    for (int j = r0; j < r1; ++j) {
      int2 p = esw[j];
      fma4(acc, __int_as_float(p.y), Tl4[(size_t)p.x * F4 + c]);
    }
    float inv = 1.0f / fmaxf((float)(r1 - r0), 1.0f);
    float4 t = Tr4[(size_t)n * F4 + c];
    float4 bb = b4[c];
    v.x = fmaf(acc.x, inv, t.x + bb.x);
    v.y = fmaf(acc.y, inv, t.y + bb.y);
    v.z = fmaf(acc.z, inv, t.z + bb.z);
    v.w = fmaf(acc.w, inv, t.w + bb.w);
    ((float4*)out)[(size_t)n * F4 + c] = v;
  }
  if constexpr (STATS) {
    __shared__ float4 redS[4][32];
    __shared__ float4 redQ[4][32];
    float4 q;
    q.x = v.x * v.x; q.y = v.y * v.y; q.z = v.z * v.z; q.w = v.w * v.w;
    float4 s = v;
    s.x += __shfl_xor(s.x, 32, 64); s.y += __shfl_xor(s.y, 32, 64);
    s.z += __shfl_xor(s.z, 32, 64); s.w += __shfl_xor(s.w, 32, 64);
    q.x += __shfl_xor(q.x, 32, 64); q.y += __shfl_xor(q.y, 32, 64);
    q.z += __shfl_xor(q.z, 32, 64); q.w += __shfl_xor(q.w, 32, 64);
    const int lane = tid & 63, wid = tid >> 6;
    if (lane < 32) { redS[wid][lane] = s; redQ[wid][lane] = q; }
    __syncthreads();
    if (tid < 32) {
      float4 S = redS[0][tid];
      float4 Q = redQ[0][tid];
#pragma unroll
      for (int w2 = 1; w2 < 4; ++w2) {
        S.x += redS[w2][tid].x; S.y += redS[w2][tid].y;
        S.z += redS[w2][tid].z; S.w += redS[w2][tid].w;
        Q.x += redQ[w2][tid].x; Q.y += redQ[w2][tid].y;
        Q.z += redQ[w2][tid].z; Q.w += redQ[w2][tid].w;
      }
      atomicAdd(&stats[tid * 4 + 0], S.x); atomicAdd(&stats[tid * 4 + 1], S.y);
      atomicAdd(&stats[tid * 4 + 2], S.z); atomicAdd(&stats[tid * 4 + 3], S.w);
      atomicAdd(&stats[128 + tid * 4 + 0], Q.x); atomicAdd(&stats[128 + tid * 4 + 1], Q.y);
      atomicAdd(&stats[128 + tid * 4 + 2], Q.z); atomicAdd(&stats[128 + tid * 4 + 3], Q.w);
    }
  }
}

// ---------- BN finalize ----------
__global__ void bn_fin(const float* __restrict__ stats, const float* __restrict__ gamma,
                       const float* __restrict__ beta, float* __restrict__ ss) {
  int f = threadIdx.x;
  float mu = stats[f] * (1.0f / (float)NN);
  float ex2 = stats[128 + f] * (1.0f / (float)NN);
  float var = ex2 - mu * mu;
  float sc = gamma[f] * rsqrtf(var + 1e-5f);
  ss[f] = sc;
  ss[128 + f] = beta[f] - mu * sc;
}

extern "C" void kernel_launch(void* const* d_in, const int* in_sizes, int n_in,
                              void* d_out, int out_size, void* d_ws, size_t ws_size,
                              hipStream_t stream) {
  (void)in_sizes; (void)n_in; (void)out_size;
  const float* x   = (const float*)d_in[0];
  const int*   ei  = (const int*)d_in[1];
  const float* ew  = (const float*)d_in[2];
  const float* Wl0 = (const float*)d_in[3];
  const float* Wr0 = (const float*)d_in[4];
  const float* b0  = (const float*)d_in[5];
  const float* Wl1 = (const float*)d_in[6];
  const float* Wr1 = (const float*)d_in[7];
  const float* b1  = (const float*)d_in[8];
  const float* Wl2 = (const float*)d_in[9];
  const float* Wr2 = (const float*)d_in[10];
  const float* b2  = (const float*)d_in[11];
  const float* g0  = (const float*)d_in[12];
  const float* be0 = (const float*)d_in[13];
  const float* g1  = (const float*)d_in[14];
  const float* be1 = (const float*)d_in[15];
  float* out = (float*)d_out;

  size_t off = 0;
  auto alloc = [&](size_t b) -> void* {
    void* p = (char*)d_ws + off;
    off += (b + 255) & ~(size_t)255;
    return p;
  };
  float* tl    = (float*)alloc((size_t)NN * 128 * 4);
  float* tr    = (float*)alloc((size_t)NN * 128 * 4);
  float* hpre  = (float*)alloc((size_t)NN * 128 * 4);
  int*   rs    = (int*)alloc((size_t)(NN + 1) * 4);
  int*   cur_d = (int*)alloc((size_t)NN * 4);
  float* stats = (float*)alloc(256 * 4);
  float* ssb   = (float*)alloc(256 * 4);
  int*   srcs  = (int*)alloc((size_t)EE * 4);
  int2*  pw    = (int2*)alloc((size_t)EE * 8);   // big: {csr_pos,w}; fallback: esw {src,w}
  int*   cs    = (int*)alloc((size_t)(NN + 1) * 4);
  int*   cur_s = (int*)alloc((size_t)NN * 4);
  float* msg   = (float*)alloc((size_t)EE * 128 * 4);  // 307.2 MB, must be last
  const bool big = ws_size >= off;

  const int EB = (EE + 255) / 256;
  if (big) {
    // ---- preprocessing: CSC order + CSR positions
    hipMemsetAsync(cur_s, 0, (size_t)NN * 4, stream);
    hipMemsetAsync(cur_d, 0, (size_t)NN * 4, stream);
    count2_k<<<EB, 256, 0, stream>>>(ei, cur_s, cur_d);
    scan_k<<<1, 1024, 0, stream>>>(cur_s, cs);
    scan_k<<<1, 1024, 0, stream>>>(cur_d, rs);
    hipMemcpyAsync(cur_s, cs, (size_t)NN * 4, hipMemcpyDeviceToDevice, stream);
    hipMemcpyAsync(cur_d, rs, (size_t)NN * 4, hipMemcpyDeviceToDevice, stream);
    fill2_k<<<EB, 256, 0, stream>>>(ei, ew, cur_s, cur_d, srcs, pw);

    // ---- layer 0
    gemm_dual<128><<<(NN + 63) / 64, 256, 0, stream>>>(x, Wl0, Wr0, nullptr, tl, tr);
    edge_scatter<32><<<(EE * 32 + 255) / 256, 256, 0, stream>>>(tl, srcs, pw, msg);
    hipMemsetAsync(stats, 0, 256 * 4, stream);
    seg_reduce<32, true><<<NN / 8, 256, 0, stream>>>(msg, tr, rs, b0, hpre, stats);
    bn_fin<<<1, 128, 0, stream>>>(stats, g0, be0, ssb);

    // ---- layer 1
    gemm_dual<128><<<(NN + 63) / 64, 256, 0, stream>>>(hpre, Wl1, Wr1, ssb, tl, tr);
    edge_scatter<32><<<(EE * 32 + 255) / 256, 256, 0, stream>>>(tl, srcs, pw, msg);
    hipMemsetAsync(stats, 0, 256 * 4, stream);
    seg_reduce<32, true><<<NN / 8, 256, 0, stream>>>(msg, tr, rs, b1, hpre, stats);
    bn_fin<<<1, 128, 0, stream>>>(stats, g1, be1, ssb);

    // ---- layer 2
    gemm_dual<64><<<(NN + 127) / 128, 256, 0, stream>>>(hpre, Wl2, Wr2, ssb, tl, tr);
    edge_scatter<16><<<(EE * 16 + 255) / 256, 256, 0, stream>>>(tl, srcs, pw, msg);
    seg_reduce<16, false><<<NN / 16, 256, 0, stream>>>(msg, tr, rs, b2, out, nullptr);
  } else {
    // ---- fallback: fused gather (R2 structure)
    hipMemsetAsync(cur_d, 0, (size_t)NN * 4, stream);
    count2_k<<<EB, 256, 0, stream>>>(ei, cur_s, cur_d);  // cur_s writes land in scratch
    hipMemsetAsync(cur_s, 0, (size_t)NN * 4, stream);
    scan_k<<<1, 1024, 0, stream>>>(cur_d, rs);
    hipMemcpyAsync(cur_d, rs, (size_t)NN * 4, hipMemcpyDeviceToDevice, stream);
    fill_k<<<EB, 256, 0, stream>>>(ei, ew, cur_d, pw);

    gemm_dual<128><<<(NN + 63) / 64, 256, 0, stream>>>(x, Wl0, Wr0, nullptr, tl, tr);
    hipMemsetAsync(stats, 0, 256 * 4, stream);
    gather_combine<32, true><<<NN / 8, 256, 0, stream>>>(tl, tr, rs, pw, b0, hpre, stats);
    bn_fin<<<1, 128, 0, stream>>>(stats, g0, be0, ssb);

    gemm_dual<128><<<(NN + 63) / 64, 256, 0, stream>>>(hpre, Wl1, Wr1, ssb, tl, tr);
    hipMemsetAsync(stats, 0, 256 * 4, stream);
    gather_combine<32, true><<<NN / 8, 256, 0, stream>>>(tl, tr, rs, pw, b1, hpre, stats);
    bn_fin<<<1, 128, 0, stream>>>(stats, g1, be1, ssb);

    gemm_dual<64><<<(NN + 127) / 128, 256, 0, stream>>>(hpre, Wl2, Wr2, ssb, tl, tr);
    gather_combine<16, false><<<NN / 16, 256, 0, stream>>>(tl, tr, rs, pw, b2, out, nullptr);
  }
}

// Round 5
// 1138.141 us; speedup vs baseline: 1.4726x; 1.4726x over previous
//
#include <hip/hip_runtime.h>

#define NN 50000
#define EE 600000

__device__ inline void fma4(float4& a, float s, const float4 w) {
  a.x = fmaf(s, w.x, a.x);
  a.y = fmaf(s, w.y, a.y);
  a.z = fmaf(s, w.z, a.z);
  a.w = fmaf(s, w.w, a.w);
}

__device__ inline ushort f2bf(float x) {  // round-to-nearest-even bf16
  unsigned u = __float_as_uint(x);
  u = (u + 0x7fffu + ((u >> 16) & 1u)) >> 16;
  return (ushort)u;
}

// ---------- CSR build ----------
__global__ void count_k(const int* __restrict__ ei, int* __restrict__ cnt) {
  int e = blockIdx.x * 256 + threadIdx.x;
  if (e < EE) atomicAdd(&cnt[ei[EE + e]], 1);
}

__global__ void scan_k(const int* __restrict__ cnt, int* __restrict__ rs) {
  __shared__ int ls[1024];
  const int t = threadIdx.x;
  const int STRIP = (NN + 1023) >> 10;  // 49
  int i0 = t * STRIP;
  int i1 = min(i0 + STRIP, NN);
  int s = 0;
  for (int i = i0; i < i1; ++i) s += cnt[i];
  ls[t] = s;
  __syncthreads();
  for (int off = 1; off < 1024; off <<= 1) {
    int v = (t >= off) ? ls[t - off] : 0;
    __syncthreads();
    ls[t] += v;
    __syncthreads();
  }
  int run = (t == 0) ? 0 : ls[t - 1];
  for (int i = i0; i < i1; ++i) { rs[i] = run; run += cnt[i]; }
  if (t == 0) rs[NN] = EE;
}

__global__ void fill_k(const int* __restrict__ ei, const float* __restrict__ ew,
                       int* __restrict__ cur, int2* __restrict__ esw) {
  int e = blockIdx.x * 256 + threadIdx.x;
  if (e < EE) {
    int d = ei[EE + e];
    int p = atomicAdd(&cur[d], 1);
    int2 v;
    v.x = ei[e];
    v.y = __float_as_int(ew[e]);
    esw[p] = v;
  }
}

__global__ void invd_k(const int* __restrict__ rs, float* __restrict__ invd) {
  int n = blockIdx.x * 256 + threadIdx.x;
  if (n < NN) {
    int d = rs[n + 1] - rs[n];
    invd[n] = 1.0f / (float)max(d, 1);
  }
}

// ---------- fused dual GEMM: Tl(bf16,col-chunked) / Tr(f32) ----------
// Tl layout: chunk c (32 cols) at Tlb + c*NN*32 ushorts; row n = 64B line.
template <int F>
__global__ __launch_bounds__(256, 3) void gemm_dual(
    const float* __restrict__ H, const float* __restrict__ Wl,
    const float* __restrict__ Wr, const float* __restrict__ ss,
    ushort* __restrict__ Tlb, float* __restrict__ Tr) {
  constexpr int K = 128;
  constexpr int Kc = 32;
  constexpr int TX = F / 4;
  constexpr int TY = 256 / TX;
  constexpr int ROWS = TY * 8;
  constexpr int HS = ROWS + 4;
  __shared__ __align__(16) float Wls[Kc][F];
  __shared__ __align__(16) float Wrs[Kc][F];
  __shared__ __align__(16) float Hs[Kc][HS];
  const int tid = threadIdx.x;
  const int tx = tid % TX, ty = tid / TX;
  const int n0 = blockIdx.x * ROWS;

  const float4 z4 = {0.f, 0.f, 0.f, 0.f};
  float4 aAA[4], aAB[4], aBA[4], aBB[4];
#pragma unroll
  for (int r = 0; r < 4; ++r) { aAA[r] = z4; aAB[r] = z4; aBA[r] = z4; aBB[r] = z4; }

  for (int kc = 0; kc < K; kc += Kc) {
    __syncthreads();
    for (int idx = tid; idx < Kc * (F / 4); idx += 256) {
      int k = idx / (F / 4), c = idx % (F / 4);
      ((float4*)(&Wls[k][0]))[c] = ((const float4*)Wl)[(kc + k) * (F / 4) + c];
      ((float4*)(&Wrs[k][0]))[c] = ((const float4*)Wr)[(kc + k) * (F / 4) + c];
    }
    for (int idx = tid; idx < ROWS * 8; idx += 256) {
      int i = idx >> 3, k4 = idx & 7;
      int nrow = n0 + i;
      float4 hv = z4;
      if (nrow < NN) hv = ((const float4*)H)[nrow * 32 + (kc >> 2) + k4];
      if (ss) {
        int gk = kc + k4 * 4;
        hv.x = fmaxf(fmaf(hv.x, ss[gk + 0], ss[128 + gk + 0]), 0.f);
        hv.y = fmaxf(fmaf(hv.y, ss[gk + 1], ss[128 + gk + 1]), 0.f);
        hv.z = fmaxf(fmaf(hv.z, ss[gk + 2], ss[128 + gk + 2]), 0.f);
        hv.w = fmaxf(fmaf(hv.w, ss[gk + 3], ss[128 + gk + 3]), 0.f);
      }
      Hs[k4 * 4 + 0][i] = hv.x;
      Hs[k4 * 4 + 1][i] = hv.y;
      Hs[k4 * 4 + 2][i] = hv.z;
      Hs[k4 * 4 + 3][i] = hv.w;
    }
    __syncthreads();
#pragma unroll 4
    for (int k = 0; k < Kc; ++k) {
      float4 wA = *(const float4*)&Wls[k][tx * 4];
      float4 wB = *(const float4*)&Wrs[k][tx * 4];
      float4 hA = *(const float4*)&Hs[k][ty * 4];
      float4 hB = *(const float4*)&Hs[k][ROWS / 2 + ty * 4];
      fma4(aAA[0], hA.x, wA); fma4(aAA[1], hA.y, wA); fma4(aAA[2], hA.z, wA); fma4(aAA[3], hA.w, wA);
      fma4(aAB[0], hA.x, wB); fma4(aAB[1], hA.y, wB); fma4(aAB[2], hA.z, wB); fma4(aAB[3], hA.w, wB);
      fma4(aBA[0], hB.x, wA); fma4(aBA[1], hB.y, wA); fma4(aBA[2], hB.z, wA); fma4(aBA[3], hB.w, wA);
      fma4(aBB[0], hB.x, wB); fma4(aBB[1], hB.y, wB); fma4(aBB[2], hB.z, wB); fma4(aBB[3], hB.w, wB);
    }
  }
  float4* Tr4 = (float4*)Tr;
  const int c0 = tx * 4;
  const int chunk = c0 >> 5;
  const int coff = c0 & 31;
#pragma unroll
  for (int r = 0; r < 4; ++r) {
    int nA = n0 + ty * 4 + r;
    if (nA < NN) {
      ushort4 u4 = {f2bf(aAA[r].x), f2bf(aAA[r].y), f2bf(aAA[r].z), f2bf(aAA[r].w)};
      *(ushort4*)(Tlb + (size_t)chunk * NN * 32 + (size_t)nA * 32 + coff) = u4;
      Tr4[(size_t)nA * TX + tx] = aAB[r];
    }
    int nB = n0 + ROWS / 2 + ty * 4 + r;
    if (nB < NN) {
      ushort4 u4 = {f2bf(aBA[r].x), f2bf(aBA[r].y), f2bf(aBA[r].z), f2bf(aBA[r].w)};
      *(ushort4*)(Tlb + (size_t)chunk * NN * 32 + (size_t)nB * 32 + coff) = u4;
      Tr4[(size_t)nB * TX + tx] = aBB[r];
    }
  }
}

// ---------- chunked gather: one 3.2MB bf16 column-chunk, L2-resident ----------
// 16 lanes per node (lane = 2 cols); one 64B line per (node,edge) read.
// Block first streams its slice of the chunk to prime its XCD's L2.
template <int F, bool STATS>
__global__ __launch_bounds__(256, 8) void gather_chunk(
    const ushort* __restrict__ Tlb, const float* __restrict__ Tr,
    const int* __restrict__ rs, const int2* __restrict__ esw,
    const float* __restrict__ invd, const float* __restrict__ bias,
    float* __restrict__ out, float* __restrict__ stats, int chunk) {
  const int tid = threadIdx.x;
  const ushort* cbase = Tlb + (size_t)chunk * NN * 32;
  __shared__ float sink;
  if (tid == 0) sink = 0.f;
  __syncthreads();
  // ---- prime: blocks with blockIdx%8==x are (heuristically) on XCD x;
  // together they stream the whole 3.2MB chunk into that XCD's L2.
  {
    const int total4 = NN * 64 / 16;  // float4 count = 200000
    const float4* cb4 = (const float4*)cbase;
    int nsl = gridDim.x >> 3;
    int sl = blockIdx.x >> 3;
    if (sl < nsl) {
      int per = (total4 + nsl - 1) / nsl;
      int i0 = sl * per;
      int i1 = min(i0 + per, total4);
      float acc = 0.f;
      for (int i = i0 + tid; i < i1; i += 256) {
        float4 t = cb4[i];
        acc += t.x + t.y + t.z + t.w;
      }
      atomicAdd(&sink, acc);  // LDS atomic: keeps the priming loads alive
    }
  }
  // ---- gather (grid = exactly NN/16 blocks; n always < NN)
  const uint* cb = (const uint*)cbase;
  const int l = tid & 15;
  const int n = blockIdx.x * 16 + (tid >> 4);
  const int r0 = rs[n], r1 = rs[n + 1];
  float2 acc = {0.f, 0.f};
  for (int j0 = r0; j0 < r1; j0 += 4) {
    int sidx[4];
    float ww[4];
#pragma unroll
    for (int u = 0; u < 4; ++u) {
      int jj = (j0 + u < r1) ? (j0 + u) : r0;
      int2 p = esw[jj];
      sidx[u] = p.x;
      ww[u] = (j0 + u < r1) ? __int_as_float(p.y) : 0.f;
    }
    uint t[4];
#pragma unroll
    for (int u = 0; u < 4; ++u) t[u] = cb[(size_t)sidx[u] * 16 + l];
#pragma unroll
    for (int u = 0; u < 4; ++u) {
      float f0 = __uint_as_float(t[u] << 16);
      float f1 = __uint_as_float(t[u] & 0xffff0000u);
      acc.x = fmaf(ww[u], f0, acc.x);
      acc.y = fmaf(ww[u], f1, acc.y);
    }
  }
  const int c0 = chunk * 32 + 2 * l;
  const float iv = invd[n];
  float2 tr = *(const float2*)(Tr + (size_t)n * F + c0);
  float2 v;
  v.x = fmaf(acc.x, iv, tr.x + bias[c0]);
  v.y = fmaf(acc.y, iv, tr.y + bias[c0 + 1]);
  float* op = out + (size_t)n * F + c0;
  __builtin_nontemporal_store(v.x, op);      // don't evict the L2-resident chunk
  __builtin_nontemporal_store(v.y, op + 1);
  if constexpr (STATS) {
    float2 s = v;
    float2 q = {v.x * v.x, v.y * v.y};
    s.x += __shfl_xor(s.x, 16, 64); s.y += __shfl_xor(s.y, 16, 64);
    q.x += __shfl_xor(q.x, 16, 64); q.y += __shfl_xor(q.y, 16, 64);
    s.x += __shfl_xor(s.x, 32, 64); s.y += __shfl_xor(s.y, 32, 64);
    q.x += __shfl_xor(q.x, 32, 64); q.y += __shfl_xor(q.y, 32, 64);
    __shared__ float2 rS[4][16];
    __shared__ float2 rQ[4][16];
    const int wid = tid >> 6, wl = tid & 63;
    if (wl < 16) { rS[wid][wl] = s; rQ[wid][wl] = q; }
    __syncthreads();
    if (tid < 16) {
      float2 S = rS[0][tid], Q = rQ[0][tid];
#pragma unroll
      for (int w2 = 1; w2 < 4; ++w2) {
        S.x += rS[w2][tid].x; S.y += rS[w2][tid].y;
        Q.x += rQ[w2][tid].x; Q.y += rQ[w2][tid].y;
      }
      int col = chunk * 32 + 2 * tid;
      atomicAdd(&stats[col], S.x);
      atomicAdd(&stats[col + 1], S.y);
      atomicAdd(&stats[128 + col], Q.x);
      atomicAdd(&stats[128 + col + 1], Q.y);
    }
  }
}

// ---------- BN finalize ----------
__global__ void bn_fin(const float* __restrict__ stats, const float* __restrict__ gamma,
                       const float* __restrict__ beta, float* __restrict__ ss) {
  int f = threadIdx.x;
  float mu = stats[f] * (1.0f / (float)NN);
  float ex2 = stats[128 + f] * (1.0f / (float)NN);
  float var = ex2 - mu * mu;
  float sc = gamma[f] * rsqrtf(var + 1e-5f);
  ss[f] = sc;
  ss[128 + f] = beta[f] - mu * sc;
}

extern "C" void kernel_launch(void* const* d_in, const int* in_sizes, int n_in,
                              void* d_out, int out_size, void* d_ws, size_t ws_size,
                              hipStream_t stream) {
  (void)in_sizes; (void)n_in; (void)out_size; (void)ws_size;
  const float* x   = (const float*)d_in[0];
  const int*   ei  = (const int*)d_in[1];
  const float* ew  = (const float*)d_in[2];
  const float* Wl0 = (const float*)d_in[3];
  const float* Wr0 = (const float*)d_in[4];
  const float* b0  = (const float*)d_in[5];
  const float* Wl1 = (const float*)d_in[6];
  const float* Wr1 = (const float*)d_in[7];
  const float* b1  = (const float*)d_in[8];
  const float* Wl2 = (const float*)d_in[9];
  const float* Wr2 = (const float*)d_in[10];
  const float* b2  = (const float*)d_in[11];
  const float* g0  = (const float*)d_in[12];
  const float* be0 = (const float*)d_in[13];
  const float* g1  = (const float*)d_in[14];
  const float* be1 = (const float*)d_in[15];
  float* out = (float*)d_out;

  size_t off = 0;
  auto alloc = [&](size_t b) -> void* {
    void* p = (char*)d_ws + off;
    off += (b + 255) & ~(size_t)255;
    return p;
  };
  ushort* tlb  = (ushort*)alloc((size_t)NN * 128 * 2);  // 12.8 MB bf16 chunked
  float* tr    = (float*)alloc((size_t)NN * 128 * 4);   // 25.6 MB
  float* hpre  = (float*)alloc((size_t)NN * 128 * 4);   // 25.6 MB
  int2*  esw   = (int2*)alloc((size_t)EE * 8);          // 4.8 MB
  int*   rs    = (int*)alloc((size_t)(NN + 1) * 4);
  int*   cur   = (int*)alloc((size_t)NN * 4);
  float* invd  = (float*)alloc((size_t)NN * 4);
  float* stats = (float*)alloc(256 * 4);
  float* ssb   = (float*)alloc(256 * 4);
  // total ~70 MB (< the 82 MB footprint proven to fit in R0-R2)

  const int EB = (EE + 255) / 256;
  const int GB = NN / 16;  // 3125 gather blocks, exact

  // ---- CSR build
  hipMemsetAsync(cur, 0, (size_t)NN * 4, stream);
  count_k<<<EB, 256, 0, stream>>>(ei, cur);
  scan_k<<<1, 1024, 0, stream>>>(cur, rs);
  hipMemcpyAsync(cur, rs, (size_t)NN * 4, hipMemcpyDeviceToDevice, stream);
  fill_k<<<EB, 256, 0, stream>>>(ei, ew, cur, esw);
  invd_k<<<(NN + 255) / 256, 256, 0, stream>>>(rs, invd);

  // ---- layer 0
  gemm_dual<128><<<(NN + 63) / 64, 256, 0, stream>>>(x, Wl0, Wr0, nullptr, tlb, tr);
  hipMemsetAsync(stats, 0, 256 * 4, stream);
  for (int c = 0; c < 4; ++c)
    gather_chunk<128, true><<<GB, 256, 0, stream>>>(tlb, tr, rs, esw, invd, b0, hpre, stats, c);
  bn_fin<<<1, 128, 0, stream>>>(stats, g0, be0, ssb);

  // ---- layer 1 (BN0+ReLU folded into GEMM staging)
  gemm_dual<128><<<(NN + 63) / 64, 256, 0, stream>>>(hpre, Wl1, Wr1, ssb, tlb, tr);
  hipMemsetAsync(stats, 0, 256 * 4, stream);
  for (int c = 0; c < 4; ++c)
    gather_chunk<128, true><<<GB, 256, 0, stream>>>(tlb, tr, rs, esw, invd, b1, hpre, stats, c);
  bn_fin<<<1, 128, 0, stream>>>(stats, g1, be1, ssb);

  // ---- layer 2 (BN1+ReLU folded; F=64 straight to d_out)
  gemm_dual<64><<<(NN + 127) / 128, 256, 0, stream>>>(hpre, Wl2, Wr2, ssb, tlb, tr);
  for (int c = 0; c < 2; ++c)
    gather_chunk<64, false><<<GB, 256, 0, stream>>>(tlb, tr, rs, esw, invd, b2, out, nullptr, c);
}